// Round 4
// baseline (454.272 us; speedup 1.0000x reference)
//
#include <hip/hip_runtime.h>

// 2-layer LSTM (H=50, B=4096, T=512, D_in=1) + FC(50->1), fused MFMA, round 18.
//
// = round-17 (16 layer-specialized waves, x/bias in K-slots, gate pre-scaling,
// merged-rcp cell, H1 ring[4]/H2 ring[2]) with the per-timestep __syncthreads
// REMOVED, replaced by LDS flag-based producer/consumer self-pacing:
//   - each wave publishes prog[gw]=step+1 (lane0 ds_write after lgkmcnt fence)
//   - one light "closer" wave per group min-reduces its group's 8 progs and
//     publishes a single done word (done0 = L0 steps complete, done1 = L1)
//   - L0@s spins done0>=s (peers' h1(s-1)) and done1>=s-3 (ring-4 flow ctl)
//   - L1@u spins done0>=u+1 (h1(u)) and done1>=u (peers' h2(u-1))
// Rationale: r15-r17 pinned VALU-busy at ~950 cyc/SIMD/iter with a ~600-cyc
// bubble that survived TLP (r16) and LDS-burst/dephasing fixes (r17 -19cyc vs
// -190 predicted) -> the bubble is the block-wide barrier coupling (everyone
// waits for the slowest wave, 513 times). Self-pacing decouples the groups;
// their dep-chain stalls interleave on each SIMD. Deadlock-free (blocked L0
// implies the laggard L1 wave is unblocked, and vice versa). Arithmetic is
// bit-identical to r17. Closers (w5,w9) and x-writer (w6) sit on 6-update
// SIMDs to even per-SIMD issue load {7,6+,6+,7}.
// B-frag layout (r2-r13-verified): k -> ks=k>>5, lane=((k>>3)&3)*16+n, j=k&7.

#define TT 512
#define HH 50
#define BT 16
#define NTHR 1024  // 16 waves
#define L2E 1.44269504f

typedef _Float16 half8 __attribute__((ext_vector_type(8)));
typedef float floatx4 __attribute__((ext_vector_type(4)));

static __device__ __forceinline__ float fexp2(float x) { return __builtin_amdgcn_exp2f(x); }
static __device__ __forceinline__ float frcp(float x)  { return __builtin_amdgcn_rcpf(x); }
static __device__ __forceinline__ int   imin(int a, int b) { return a < b ? a : b; }

// ---- flag helpers (LDS, block-scope) ----
static __device__ __forceinline__ int ldv(const int* p) { return *(volatile const int*)p; }

static __device__ __forceinline__ void spin_ge(const int* p, int v) {
    while (ldv(p) < v) {}
    __asm__ volatile("" ::: "memory");   // data reads below must not hoist above
}

static __device__ __forceinline__ void publish(int* p, int v, int ln) {
    __asm__ volatile("s_waitcnt lgkmcnt(0)" ::: "memory");  // h-writes drained
    if (ln == 0) *(volatile int*)p = v;
}

static __device__ __forceinline__ void close_group(const int* prog, int* done,
                                                   int v, int ln) {
    for (;;) {
        __asm__ volatile("" ::: "memory");                   // force re-read
        int4 A = *(const int4*)(prog);
        int4 B = *(const int4*)(prog + 4);
        int mn = imin(imin(imin(A.x, A.y), imin(A.z, A.w)),
                      imin(imin(B.x, B.y), imin(B.z, B.w)));
        if (mn >= v) break;
    }
    __asm__ volatile("" ::: "memory");
    if (ln == 0) *(volatile int*)done = v;
}

// PRE-SCALED cell update: inputs are already s_g*gate (s = -log2e, -log2e,
// -2log2e, -log2e for i,f,g,o). c' = R*[c*(1+Ei)(1+Eg) + (1-Eg)(1+Ef)],
// R = rcp((1+Ef)(1+Ei)(1+Eg)); h = sig(o)*tanh(c'), c clamped (NaN guard).
static __device__ __forceinline__ float cell_update(float gi, float gf, float gg,
                                                    float go, float& c) {
    float Ei = fexp2(gi);
    float Eg = fexp2(gg);
    float Ef = fexp2(gf);
    float p1 = (1.0f + Ei) * (1.0f + Eg);
    float fe = 1.0f + Ef;
    float R  = frcp(fe * p1);
    c = R * (c * p1 + (1.0f - Eg) * fe);
    float cl = fminf(fmaxf(c, -18.0f), 18.0f);
    float Eo = fexp2(go);
    float Ec = fexp2(cl * (-2.0f * L2E));
    float Ro = frcp((1.0f + Eo) * (1.0f + Ec));
    return (1.0f - Ec) * Ro;
}

#define MFMA(a, b, c) __builtin_amdgcn_mfma_f32_16x16x32_f16((a), (b), (c), 0, 0, 0)

// ---------------- layer-0 waves: NJ tile-jobs, tiles tbase..tbase+NJ-1 ----------------
// Step s computes h1(s) from h1(s-1) = H1[(s-1)&3]; writes H1[s&3].
// XW wave maintains x slot 51 of H1[s&3] with x(s+1). CL wave is group closer.
template<int NJ, bool XW, bool CL>
static __device__ __forceinline__ void run_l0(
    int tbase, int gw, int ln, _Float16 (*H1)[1024], const float* xs,
    int* prog0, int* done0, const int* done1,
    const float* __restrict__ W_ih0, const float* __restrict__ W_hh0,
    const float* __restrict__ b_ih0, const float* __restrict__ b_hh0)
{
    const int m = ln & 15, q = ln >> 4;
    const float GSC[4] = { -L2E, -L2E, -2.0f * L2E, -L2E };

    half8 a0[NJ][2];
    float c[NJ];
    int   widx[NJ];
#pragma unroll
    for (int j = 0; j < NJ; ++j) {
        const int  tau  = tbase + j;
        const int  uA   = 4 * tau + (m >> 2);
        const int  gA   = m & 3;
        const bool rokA = (uA < HH);
        const int  wrow = gA * HH + uA;
        const float sA  = GSC[gA];
#pragma unroll
        for (int ks = 0; ks < 2; ++ks) {
            half8 h8;
#pragma unroll
            for (int jj = 0; jj < 8; ++jj) {
                int k = ks * 32 + q * 8 + jj;
                float w = 0.f;
                if (rokA) {
                    if (k < HH)       w = W_hh0[wrow * HH + k];
                    else if (k == 50) w = b_ih0[wrow] + b_hh0[wrow];
                    else if (k == 51) w = W_ih0[wrow];      // W_ih0 is [4H x 1]
                }
                h8[jj] = (_Float16)(sA * w);
            }
            a0[j][ks] = h8;
        }
        const int uC = 4 * tau + q;
        const int kh = (uC < HH) ? uC : (uC + 2);   // dummies 50,51 -> 52,53
        widx[j] = ((kh >> 5) * 64 + ((kh >> 3) & 3) * 16 + m) * 8 + (kh & 7);
        c[j] = 0.f;
    }

    // ---- step 0: h1(0) from x(0) only (h=0), scalar path -> H1[0] ----
    {
        const float xv = xs[m];
#pragma unroll
        for (int j = 0; j < NJ; ++j) {
            const int  uC = 4 * (tbase + j) + q;
            const bool vC = (uC < HH);
            float g4[4];
#pragma unroll
            for (int g = 0; g < 4; ++g) {
                int rg = g * HH + (vC ? uC : 0);
                g4[g] = vC ? GSC[g] * ((b_ih0[rg] + b_hh0[rg]) + W_ih0[rg] * xv) : 0.f;
            }
            float h = cell_update(g4[0], g4[1], g4[2], g4[3], c[j]);
            H1[0][widx[j]] = (_Float16)h;
        }
        publish(&prog0[gw], 1, ln);
        if (CL) close_group(prog0, done0, 1, ln);
    }

    const floatx4 ZERO = { 0.f, 0.f, 0.f, 0.f };
    for (int s = 1; s <= 511; ++s) {
        spin_ge(done0, s);          // peers' h1(s-1) (incl. x(s) in slot 51)
        spin_ge(done1, s - 3);      // ring-4 flow control vs L1 (auto-true s<=3)
        const _Float16* bufR = H1[(s - 1) & 3];
        _Float16*       bufW = H1[s & 3];
        half8 b0 = *(const half8*)&bufR[(0  + ln) * 8];
        half8 b1 = *(const half8*)&bufR[(64 + ln) * 8];
        floatx4 acc[NJ];
#pragma unroll
        for (int j = 0; j < NJ; ++j) {
            floatx4 a = MFMA(a0[j][0], b0, ZERO);
            acc[j] = MFMA(a0[j][1], b1, a);
        }
#pragma unroll
        for (int j = 0; j < NJ; ++j) {
            float h = cell_update(acc[j][0], acc[j][1], acc[j][2], acc[j][3], c[j]);
            bufW[widx[j]] = (_Float16)h;
        }
        if (XW) {
            if (ln < 16)            // x(s+1) -> slot 51; s=511 reads zero pad
                bufW[(96 + ln) * 8 + 3] = (_Float16)xs[(s + 1) * BT + ln];
        }
        publish(&prog0[gw], s + 1, ln);
        if (CL) close_group(prog0, done0, s + 1, ln);
    }
}

// ---------------- layer-1 waves: NJ tile-jobs, tiles tbase..tbase+NJ-1 ----------------
// Step u computes h2(u) from h1(u) = H1[u&3] and h2(u-1) = H2[(u+1)&1];
// writes H2[u&1]. CL wave is group closer.
template<int NJ, bool CL>
static __device__ __forceinline__ void run_l1(
    int tbase, int gw, int ln, _Float16 (*H1)[1024], _Float16 (*H2)[1024],
    int* prog1, const int* done0, int* done1,
    const float* __restrict__ W_ih1, const float* __restrict__ W_hh1,
    const float* __restrict__ b_ih1, const float* __restrict__ b_hh1)
{
    const int m = ln & 15, q = ln >> 4;
    const float GSC[4] = { -L2E, -L2E, -2.0f * L2E, -L2E };

    half8 a1[NJ][4];       // virtual K=128: [W_ih1 | bias@50 | 0 | W_hh1@64.. | 0]
    float c[NJ];
    int   widx[NJ];
#pragma unroll
    for (int j = 0; j < NJ; ++j) {
        const int  tau  = tbase + j;
        const int  uA   = 4 * tau + (m >> 2);
        const int  gA   = m & 3;
        const bool rokA = (uA < HH);
        const int  wrow = gA * HH + uA;
        const float sA  = GSC[gA];
#pragma unroll
        for (int ks = 0; ks < 4; ++ks) {
            half8 h8;
#pragma unroll
            for (int jj = 0; jj < 8; ++jj) {
                int k = ks * 32 + q * 8 + jj;
                float w = 0.f;
                if (rokA) {
                    if (k < HH)                      w = W_ih1[wrow * HH + k];
                    else if (k == 50)                w = b_ih1[wrow] + b_hh1[wrow];
                    else if (k >= 64 && k < 64 + HH) w = W_hh1[wrow * HH + (k - 64)];
                }
                h8[jj] = (_Float16)(sA * w);
            }
            a1[j][ks] = h8;
        }
        const int uC = 4 * tau + q;
        const int kh = (uC < HH) ? uC : (uC + 2);   // dummies -> 52,53 (zero-A)
        widx[j] = ((kh >> 5) * 64 + ((kh >> 3) & 3) * 16 + m) * 8 + (kh & 7);
        c[j] = 0.f;
    }

    const floatx4 ZERO = { 0.f, 0.f, 0.f, 0.f };
    for (int u = 0; u <= 511; ++u) {
        spin_ge(done0, u + 1);      // h1(u) ready (L0 completed step u)
        spin_ge(done1, u);          // peers' h2(u-1) ready (auto-true u=0)
        const _Float16* h1R = H1[u & 3];
        const _Float16* h2R = H2[(u + 1) & 1];   // == (u-1)&1; zeros at u=0
        _Float16*       h2W = H2[u & 1];
        half8 p0 = *(const half8*)&h1R[(0  + ln) * 8];
        half8 p1 = *(const half8*)&h1R[(64 + ln) * 8];
        half8 b2 = *(const half8*)&h2R[(0  + ln) * 8];
        half8 b3 = *(const half8*)&h2R[(64 + ln) * 8];
        floatx4 acc[NJ];
#pragma unroll
        for (int j = 0; j < NJ; ++j) {
            floatx4 a = MFMA(a1[j][0], p0, ZERO);
            a = MFMA(a1[j][1], p1, a);
            a = MFMA(a1[j][2], b2, a);
            acc[j] = MFMA(a1[j][3], b3, a);
        }
#pragma unroll
        for (int j = 0; j < NJ; ++j) {
            float h = cell_update(acc[j][0], acc[j][1], acc[j][2], acc[j][3], c[j]);
            h2W[widx[j]] = (_Float16)h;
        }
        publish(&prog1[gw], u + 1, ln);
        if (CL) close_group(prog1, done1, u + 1, ln);
    }
}

__global__ __launch_bounds__(NTHR, 4) void lstm_mfma(
    const float* __restrict__ x,
    const float* __restrict__ W_ih0, const float* __restrict__ W_hh0,
    const float* __restrict__ b_ih0, const float* __restrict__ b_hh0,
    const float* __restrict__ W_ih1, const float* __restrict__ W_hh1,
    const float* __restrict__ b_ih1, const float* __restrict__ b_hh1,
    const float* __restrict__ W_fc,  const float* __restrict__ b_fc,
    float* __restrict__ out)
{
    __shared__ __align__(16) _Float16 H1[4][1024];   // h1 ring + bias/x slots
    __shared__ __align__(16) _Float16 H2[2][1024];   // h2 ring
    __shared__ float xs[(TT + 1) * BT];              // +1 zero pad row
    __shared__ __align__(16) int prog0[8], prog1[8];
    __shared__ int gdone[2];                         // [0]=done0(L0), [1]=done1(L1)

    const int tid = threadIdx.x;
    const int ln  = tid & 63;
    const int wv  = tid >> 6;              // 0..15
    const int b0g = blockIdx.x * BT;

    // ---------------- one-time staging ----------------
    for (int i = tid; i < BT * TT; i += NTHR) {
        int b = i & 15, t = i >> 4;
        xs[t * BT + b] = x[(size_t)(b0g + b) * TT + t];
    }
    if (tid < BT) xs[TT * BT + tid] = 0.f;
    for (int i = tid; i < 4 * 1024; i += NTHR) ((_Float16*)H1)[i] = (_Float16)0.f;
    for (int i = tid; i < 2 * 1024; i += NTHR) ((_Float16*)H2)[i] = (_Float16)0.f;
    if (tid < 8)  { prog0[tid] = 0; prog1[tid] = 0; }
    if (tid < 2)  gdone[tid] = 0;
    __syncthreads();
    if (tid < 16) {
        // bias slot k=50 (ks=1, lane 32+n, j=2) == 1.0, all 4 ring buffers
#pragma unroll
        for (int r = 0; r < 4; ++r) H1[r][(96 + tid) * 8 + 2] = (_Float16)1.0f;
        // x(1) -> slot k=51 of H1[0] (read by L0 at s=1)
        H1[0][(96 + tid) * 8 + 3] = (_Float16)xs[BT + tid];
    }
    __syncthreads();                       // last block-wide barrier

    // job split (13 L0 jobs on waves 0-7, 13 L1 jobs on waves 8-15):
    //   L0: w0-w4: 2 jobs; w5(closer),w6(x-writer),w7: 1 job
    //   L1: w8,w10: 1 job; w9: 1 job (closer); w11-w15: 2 jobs
    // per-SIMD update counts {7,6,6,7}; closers on the 6-update SIMDs 1.
    if (wv < 8) {
        if (wv < 5)
            run_l0<2, false, false>(2 * wv, wv, ln, H1, xs,
                                    prog0, &gdone[0], &gdone[1],
                                    W_ih0, W_hh0, b_ih0, b_hh0);
        else if (wv == 5)
            run_l0<1, false, true>(10, 5, ln, H1, xs,
                                   prog0, &gdone[0], &gdone[1],
                                   W_ih0, W_hh0, b_ih0, b_hh0);
        else if (wv == 6)
            run_l0<1, true, false>(11, 6, ln, H1, xs,
                                   prog0, &gdone[0], &gdone[1],
                                   W_ih0, W_hh0, b_ih0, b_hh0);
        else
            run_l0<1, false, false>(12, 7, ln, H1, xs,
                                    prog0, &gdone[0], &gdone[1],
                                    W_ih0, W_hh0, b_ih0, b_hh0);
    } else {
        const int w = wv - 8;
        if (w == 1)
            run_l1<1, true>(1, 1, ln, H1, H2, prog1, &gdone[0], &gdone[1],
                            W_ih1, W_hh1, b_ih1, b_hh1);
        else if (w < 3)
            run_l1<1, false>(w, w, ln, H1, H2, prog1, &gdone[0], &gdone[1],
                             W_ih1, W_hh1, b_ih1, b_hh1);
        else
            run_l1<2, false>(3 + 2 * (w - 3), w, ln, H1, H2,
                             prog1, &gdone[0], &gdone[1],
                             W_ih1, W_hh1, b_ih1, b_hh1);
    }

    // -------- FC epilogue: h2(511) in H2[1]; wait for all L1 complete --------
    if (tid < BT) {
        spin_ge(&gdone[1], 512);
        float a = b_fc[0];
        for (int u = 0; u < HH; ++u) {
            int idx = ((u >> 5) * 64 + ((u >> 3) & 3) * 16 + tid) * 8 + (u & 7);
            a = fmaf((float)H2[1][idx], W_fc[u], a);
        }
        out[b0g + tid] = a;
    }
}

extern "C" void kernel_launch(void* const* d_in, const int* in_sizes, int n_in,
                              void* d_out, int out_size, void* d_ws, size_t ws_size,
                              hipStream_t stream) {
    const float* x     = (const float*)d_in[0];
    const float* W_ih0 = (const float*)d_in[1];
    const float* W_hh0 = (const float*)d_in[2];
    const float* b_ih0 = (const float*)d_in[3];
    const float* b_hh0 = (const float*)d_in[4];
    const float* W_ih1 = (const float*)d_in[5];
    const float* W_hh1 = (const float*)d_in[6];
    const float* b_ih1 = (const float*)d_in[7];
    const float* b_hh1 = (const float*)d_in[8];
    const float* W_fc  = (const float*)d_in[9];
    const float* b_fc  = (const float*)d_in[10];
    float* out = (float*)d_out;

    dim3 grid(4096 / BT);   // 256 blocks = 1/CU
    dim3 block(NTHR);       // 16 waves
    lstm_mfma<<<grid, block, 0, stream>>>(x, W_ih0, W_hh0, b_ih0, b_hh0,
                                          W_ih1, W_hh1, b_ih1, b_hh1,
                                          W_fc, b_fc, out);
}

// Round 5
// 412.313 us; speedup vs baseline: 1.1018x; 1.1018x over previous
//
#include <hip/hip_runtime.h>

// 2-layer LSTM (H=50, B=4096, T=512, D_in=1) + FC(50->1), fused MFMA, round 19.
//
// = round-17 arithmetic EXACTLY (16 layer-specialized waves, x/bias in K-slots,
// gate pre-scaling, merged-rcp cell, H1 ring[4]/H2 ring[2]; bit-identical
// results) with the per-step __syncthreads replaced by a ONE-HOP counter
// protocol (r18's two-hop closer design cost +437 cyc/iter edge latency):
//   - cnt0/cnt1 = monotonic LDS counters; each wave ds_add's 1 per completed
//     step (lane0, after lgkmcnt(0) drain). All 8 peers done step s-1 <=>
//     cnt0 >= 8s: single-word compare, no min-tree, no closer wave.
//   - L0@s waits cnt0>=8s (peers' h1(s-1) + x slot) and cnt1>=8(s-3)
//     (H1 ring-4 reuse safety). L1@u waits cnt0>=8(u+1) (h1(u) ready) and
//     cnt1>=8u (peers' h2(u-1) + H2 ring-2 safety). FC waits cnt1>=4096.
//     Deadlock-free: the min-step wave of the laggard group always has both
//     conditions satisfied (proven by min-step argument over monotone cnts).
//   - polls: 2x b32 volatile reads + s_sleep(1) backoff -> ~10 ops/step.
//   - main loops unrolled x4 -> ring bases compile-time, no per-step addr math.
// Goal: let the L0/L1 groups drift (<=3 steps) so each SIMD's 2 L0 + 2 L1
// waves sit at different micro-phases and fill each other's ds_read/MFMA/
// trans-chain latency (the ~600 cyc/iter bubble that block-wide barriers
// re-align 513 times; r16 TLP and r17 lag-2 both failed to break it).
// B-frag layout (r2-r13-verified): k -> ks=k>>5, lane=((k>>3)&3)*16+n, j=k&7.

#define TT 512
#define HH 50
#define BT 16
#define NTHR 1024  // 16 waves
#define L2E 1.44269504f

typedef _Float16 half8 __attribute__((ext_vector_type(8)));
typedef float floatx4 __attribute__((ext_vector_type(4)));

static __device__ __forceinline__ float fexp2(float x) { return __builtin_amdgcn_exp2f(x); }
static __device__ __forceinline__ float frcp(float x)  { return __builtin_amdgcn_rcpf(x); }

// ---- one-hop counter sync (LDS, block-scope) ----
static __device__ __forceinline__ void wait2(const int* cnt, int need0, int need1) {
    int a = ((volatile const int*)cnt)[0];
    int b = ((volatile const int*)cnt)[1];
    while (a < need0 || b < need1) {
        __builtin_amdgcn_s_sleep(1);
        a = ((volatile const int*)cnt)[0];
        b = ((volatile const int*)cnt)[1];
    }
    __asm__ volatile("" ::: "memory");   // data reads below must not hoist above
}

static __device__ __forceinline__ void publish(int* p, int ln) {
    __asm__ volatile("s_waitcnt lgkmcnt(0)" ::: "memory");  // h-writes drained
    if (ln == 0) atomicAdd(p, 1);
}

// PRE-SCALED cell update (identical to r17, bit-for-bit): inputs are s_g*gate
// (s = -log2e, -log2e, -2log2e, -log2e for i,f,g,o).
// c' = R*[c*(1+Ei)(1+Eg) + (1-Eg)(1+Ef)], R = rcp((1+Ef)(1+Ei)(1+Eg));
// h = sig(o)*tanh(c'), c clamped (NaN guard).
static __device__ __forceinline__ float cell_update(float gi, float gf, float gg,
                                                    float go, float& c) {
    float Ei = fexp2(gi);
    float Eg = fexp2(gg);
    float Ef = fexp2(gf);
    float p1 = (1.0f + Ei) * (1.0f + Eg);
    float fe = 1.0f + Ef;
    float R  = frcp(fe * p1);
    c = R * (c * p1 + (1.0f - Eg) * fe);
    float cl = fminf(fmaxf(c, -18.0f), 18.0f);
    float Eo = fexp2(go);
    float Ec = fexp2(cl * (-2.0f * L2E));
    float Ro = frcp((1.0f + Eo) * (1.0f + Ec));
    return (1.0f - Ec) * Ro;
}

#define MFMA(a, b, c) __builtin_amdgcn_mfma_f32_16x16x32_f16((a), (b), (c), 0, 0, 0)

// ---------------- layer-0 waves: NJ tile-jobs, tiles tbase..tbase+NJ-1 ----------------
// Step s computes h1(s) from h1(s-1) = H1[(s-1)&3]; writes H1[s&3].
// XW wave maintains x slot 51 of H1[s&3] with x(s+1).
template<int NJ, bool XW>
static __device__ __forceinline__ void run_l0(
    int tbase, int ln, _Float16 (*H1)[1024], const float* xs, int* cnt,
    const float* __restrict__ W_ih0, const float* __restrict__ W_hh0,
    const float* __restrict__ b_ih0, const float* __restrict__ b_hh0)
{
    const int m = ln & 15, q = ln >> 4;
    const float GSC[4] = { -L2E, -L2E, -2.0f * L2E, -L2E };

    half8 a0[NJ][2];
    float c[NJ];
    int   widx[NJ];
#pragma unroll
    for (int j = 0; j < NJ; ++j) {
        const int  tau  = tbase + j;
        const int  uA   = 4 * tau + (m >> 2);
        const int  gA   = m & 3;
        const bool rokA = (uA < HH);
        const int  wrow = gA * HH + uA;
        const float sA  = GSC[gA];
#pragma unroll
        for (int ks = 0; ks < 2; ++ks) {
            half8 h8;
#pragma unroll
            for (int jj = 0; jj < 8; ++jj) {
                int k = ks * 32 + q * 8 + jj;
                float w = 0.f;
                if (rokA) {
                    if (k < HH)       w = W_hh0[wrow * HH + k];
                    else if (k == 50) w = b_ih0[wrow] + b_hh0[wrow];
                    else if (k == 51) w = W_ih0[wrow];      // W_ih0 is [4H x 1]
                }
                h8[jj] = (_Float16)(sA * w);
            }
            a0[j][ks] = h8;
        }
        const int uC = 4 * tau + q;
        const int kh = (uC < HH) ? uC : (uC + 2);   // dummies 50,51 -> 52,53
        widx[j] = ((kh >> 5) * 64 + ((kh >> 3) & 3) * 16 + m) * 8 + (kh & 7);
        c[j] = 0.f;
    }

    // ---- step 0: h1(0) from x(0) only (h=0), scalar path -> H1[0] ----
    {
        const float xv = xs[m];
#pragma unroll
        for (int j = 0; j < NJ; ++j) {
            const int  uC = 4 * (tbase + j) + q;
            const bool vC = (uC < HH);
            float g4[4];
#pragma unroll
            for (int g = 0; g < 4; ++g) {
                int rg = g * HH + (vC ? uC : 0);
                g4[g] = vC ? GSC[g] * ((b_ih0[rg] + b_hh0[rg]) + W_ih0[rg] * xv) : 0.f;
            }
            float h = cell_update(g4[0], g4[1], g4[2], g4[3], c[j]);
            H1[0][widx[j]] = (_Float16)h;
        }
        publish(&cnt[0], ln);
    }

    const floatx4 ZERO = { 0.f, 0.f, 0.f, 0.f };

#define L0STEP(SS, RB, WB)                                                  \
    {                                                                       \
        const int s_ = (SS);                                                \
        wait2(cnt, 8 * s_, 8 * (s_ - 3));                                   \
        const _Float16* bufR = H1[(RB)];                                    \
        _Float16*       bufW = H1[(WB)];                                    \
        half8 b0 = *(const half8*)&bufR[(0  + ln) * 8];                     \
        half8 b1 = *(const half8*)&bufR[(64 + ln) * 8];                     \
        floatx4 acc[NJ];                                                    \
        _Pragma("unroll")                                                   \
        for (int j = 0; j < NJ; ++j) {                                      \
            floatx4 a = MFMA(a0[j][0], b0, ZERO);                           \
            acc[j] = MFMA(a0[j][1], b1, a);                                 \
        }                                                                   \
        _Pragma("unroll")                                                   \
        for (int j = 0; j < NJ; ++j) {                                      \
            float h = cell_update(acc[j][0], acc[j][1], acc[j][2], acc[j][3], c[j]); \
            bufW[widx[j]] = (_Float16)h;                                    \
        }                                                                   \
        if (XW) {                                                           \
            if (ln < 16)            /* x(s+1) -> slot 51; s=511 reads pad */ \
                bufW[(96 + ln) * 8 + 3] = (_Float16)xs[(s_ + 1) * BT + ln]; \
        }                                                                   \
        publish(&cnt[0], ln);                                               \
    }

    // s = 1..508 in quads (ring phases (0,1)(1,2)(2,3)(3,0)), tail 509-511
    for (int k = 0; k < 127; ++k) {
        const int s0 = 4 * k + 1;
        L0STEP(s0,     0, 1);
        L0STEP(s0 + 1, 1, 2);
        L0STEP(s0 + 2, 2, 3);
        L0STEP(s0 + 3, 3, 0);
    }
    L0STEP(509, 0, 1);
    L0STEP(510, 1, 2);
    L0STEP(511, 2, 3);
#undef L0STEP
}

// ---------------- layer-1 waves: NJ tile-jobs, tiles tbase..tbase+NJ-1 ----------------
// Step u computes h2(u) from h1(u) = H1[u&3] and h2(u-1) = H2[(u+1)&1];
// writes H2[u&1].
template<int NJ>
static __device__ __forceinline__ void run_l1(
    int tbase, int ln, _Float16 (*H1)[1024], _Float16 (*H2)[1024], int* cnt,
    const float* __restrict__ W_ih1, const float* __restrict__ W_hh1,
    const float* __restrict__ b_ih1, const float* __restrict__ b_hh1)
{
    const int m = ln & 15, q = ln >> 4;
    const float GSC[4] = { -L2E, -L2E, -2.0f * L2E, -L2E };

    half8 a1[NJ][4];       // virtual K=128: [W_ih1 | bias@50 | 0 | W_hh1@64.. | 0]
    float c[NJ];
    int   widx[NJ];
#pragma unroll
    for (int j = 0; j < NJ; ++j) {
        const int  tau  = tbase + j;
        const int  uA   = 4 * tau + (m >> 2);
        const int  gA   = m & 3;
        const bool rokA = (uA < HH);
        const int  wrow = gA * HH + uA;
        const float sA  = GSC[gA];
#pragma unroll
        for (int ks = 0; ks < 4; ++ks) {
            half8 h8;
#pragma unroll
            for (int jj = 0; jj < 8; ++jj) {
                int k = ks * 32 + q * 8 + jj;
                float w = 0.f;
                if (rokA) {
                    if (k < HH)                      w = W_ih1[wrow * HH + k];
                    else if (k == 50)                w = b_ih1[wrow] + b_hh1[wrow];
                    else if (k >= 64 && k < 64 + HH) w = W_hh1[wrow * HH + (k - 64)];
                }
                h8[jj] = (_Float16)(sA * w);
            }
            a1[j][ks] = h8;
        }
        const int uC = 4 * tau + q;
        const int kh = (uC < HH) ? uC : (uC + 2);   // dummies -> 52,53 (zero-A)
        widx[j] = ((kh >> 5) * 64 + ((kh >> 3) & 3) * 16 + m) * 8 + (kh & 7);
        c[j] = 0.f;
    }

    const floatx4 ZERO = { 0.f, 0.f, 0.f, 0.f };

#define L1STEP(UU, RB1, RB2, WB2)                                           \
    {                                                                       \
        const int u_ = (UU);                                                \
        wait2(cnt, 8 * (u_ + 1), 8 * u_);                                   \
        const _Float16* h1R = H1[(RB1)];                                    \
        const _Float16* h2R = H2[(RB2)];                                    \
        _Float16*       h2W = H2[(WB2)];                                    \
        half8 p0 = *(const half8*)&h1R[(0  + ln) * 8];                      \
        half8 p1 = *(const half8*)&h1R[(64 + ln) * 8];                      \
        half8 b2 = *(const half8*)&h2R[(0  + ln) * 8];                      \
        half8 b3 = *(const half8*)&h2R[(64 + ln) * 8];                      \
        floatx4 acc[NJ];                                                    \
        _Pragma("unroll")                                                   \
        for (int j = 0; j < NJ; ++j) {                                      \
            floatx4 a = MFMA(a1[j][0], p0, ZERO);                           \
            a = MFMA(a1[j][1], p1, a);                                      \
            a = MFMA(a1[j][2], b2, a);                                      \
            acc[j] = MFMA(a1[j][3], b3, a);                                 \
        }                                                                   \
        _Pragma("unroll")                                                   \
        for (int j = 0; j < NJ; ++j) {                                      \
            float h = cell_update(acc[j][0], acc[j][1], acc[j][2], acc[j][3], c[j]); \
            h2W[widx[j]] = (_Float16)h;                                     \
        }                                                                   \
        publish(&cnt[1], ln);                                               \
    }

    // u = 0..511 in quads: (u&3, (u+1)&1, u&1) = (0,1,0)(1,0,1)(2,1,0)(3,0,1)
    for (int k = 0; k < 128; ++k) {
        const int u0 = 4 * k;
        L1STEP(u0,     0, 1, 0);
        L1STEP(u0 + 1, 1, 0, 1);
        L1STEP(u0 + 2, 2, 1, 0);
        L1STEP(u0 + 3, 3, 0, 1);
    }
#undef L1STEP
}

__global__ __launch_bounds__(NTHR, 4) void lstm_mfma(
    const float* __restrict__ x,
    const float* __restrict__ W_ih0, const float* __restrict__ W_hh0,
    const float* __restrict__ b_ih0, const float* __restrict__ b_hh0,
    const float* __restrict__ W_ih1, const float* __restrict__ W_hh1,
    const float* __restrict__ b_ih1, const float* __restrict__ b_hh1,
    const float* __restrict__ W_fc,  const float* __restrict__ b_fc,
    float* __restrict__ out)
{
    __shared__ __align__(16) _Float16 H1[4][1024];   // h1 ring + bias/x slots
    __shared__ __align__(16) _Float16 H2[2][1024];   // h2 ring
    __shared__ float xs[(TT + 1) * BT];              // +1 zero pad row
    __shared__ __align__(8) int cnt[2];              // [0]=L0 steps, [1]=L1 steps

    const int tid = threadIdx.x;
    const int ln  = tid & 63;
    const int wv  = tid >> 6;              // 0..15
    const int b0g = blockIdx.x * BT;

    // ---------------- one-time staging ----------------
    for (int i = tid; i < BT * TT; i += NTHR) {
        int b = i & 15, t = i >> 4;
        xs[t * BT + b] = x[(size_t)(b0g + b) * TT + t];
    }
    if (tid < BT) xs[TT * BT + tid] = 0.f;
    for (int i = tid; i < 4 * 1024; i += NTHR) ((_Float16*)H1)[i] = (_Float16)0.f;
    for (int i = tid; i < 2 * 1024; i += NTHR) ((_Float16*)H2)[i] = (_Float16)0.f;
    if (tid < 2) cnt[tid] = 0;
    __syncthreads();
    if (tid < 16) {
        // bias slot k=50 (ks=1, lane 32+n, j=2) == 1.0, all 4 ring buffers
#pragma unroll
        for (int r = 0; r < 4; ++r) H1[r][(96 + tid) * 8 + 2] = (_Float16)1.0f;
        // x(1) -> slot k=51 of H1[0] (read by L0 at s=1)
        H1[0][(96 + tid) * 8 + 3] = (_Float16)xs[BT + tid];
    }
    __syncthreads();                       // last block-wide barrier

    // job split (13 L0 jobs on waves 0-7, 13 L1 jobs on waves 8-15):
    //   L0: w0-w4: 2 jobs; w5, w6(x-writer), w7: 1 job
    //   L1: w8,w9,w10: 1 job; w11-w15: 2 jobs
    // per-SIMD update counts {7,6,6,7} under wave->SIMD = wv&3.
    if (wv < 8) {
        if (wv < 5)
            run_l0<2, false>(2 * wv, ln, H1, xs, cnt, W_ih0, W_hh0, b_ih0, b_hh0);
        else if (wv == 6)
            run_l0<1, true>(11, ln, H1, xs, cnt, W_ih0, W_hh0, b_ih0, b_hh0);
        else
            run_l0<1, false>(wv == 5 ? 10 : 12, ln, H1, xs, cnt,
                             W_ih0, W_hh0, b_ih0, b_hh0);
    } else {
        const int w = wv - 8;
        if (w < 3)
            run_l1<1>(w, ln, H1, H2, cnt, W_ih1, W_hh1, b_ih1, b_hh1);
        else
            run_l1<2>(3 + 2 * (w - 3), ln, H1, H2, cnt,
                      W_ih1, W_hh1, b_ih1, b_hh1);
    }

    // -------- FC epilogue: h2(511) in H2[1]; wait for all L1 steps --------
    if (tid < BT) {
        wait2(cnt, 0, 8 * 512);
        float a = b_fc[0];
        for (int u = 0; u < HH; ++u) {
            int idx = ((u >> 5) * 64 + ((u >> 3) & 3) * 16 + tid) * 8 + (u & 7);
            a = fmaf((float)H2[1][idx], W_fc[u], a);
        }
        out[b0g + tid] = a;
    }
}

extern "C" void kernel_launch(void* const* d_in, const int* in_sizes, int n_in,
                              void* d_out, int out_size, void* d_ws, size_t ws_size,
                              hipStream_t stream) {
    const float* x     = (const float*)d_in[0];
    const float* W_ih0 = (const float*)d_in[1];
    const float* W_hh0 = (const float*)d_in[2];
    const float* b_ih0 = (const float*)d_in[3];
    const float* b_hh0 = (const float*)d_in[4];
    const float* W_ih1 = (const float*)d_in[5];
    const float* W_hh1 = (const float*)d_in[6];
    const float* b_ih1 = (const float*)d_in[7];
    const float* b_hh1 = (const float*)d_in[8];
    const float* W_fc  = (const float*)d_in[9];
    const float* b_fc  = (const float*)d_in[10];
    float* out = (float*)d_out;

    dim3 grid(4096 / BT);   // 256 blocks = 1/CU
    dim3 block(NTHR);       // 16 waves
    lstm_mfma<<<grid, block, 0, stream>>>(x, W_ih0, W_hh0, b_ih0, b_hh0,
                                          W_ih1, W_hh1, b_ih1, b_hh1,
                                          W_fc, b_fc, out);
}

// Round 6
// 363.730 us; speedup vs baseline: 1.2489x; 1.1336x over previous
//
#include <hip/hip_runtime.h>

// 2-layer LSTM (H=50, B=4096, T=512, D_in=1) + FC(50->1), fused MFMA, round 20.
//
// = round-17 EXACTLY (16 layer-specialized waves, x/bias in K-slots, gate
// pre-scaling, merged-rcp cell, H1 ring[4]/H2 ring[2], one s_barrier/step --
// the best measured structure, 337us; r18/r19 proved software sync loses to
// s_barrier) with three SCHEDULING-ONLY edits (no arithmetic change, absmax
// must be bit-identical):
//  1) per-job fusion: {MFMA chain_j -> update_j -> write_j} instead of
//     all-MFMAs-then-all-updates. Job j+1's MFMAs are independent of job j's
//     update -> MFMA pipe and trans pipe overlap WITHIN a wave; first update
//     starts ~60cyc after the reads instead of after the whole MFMA burst.
//     (r15-r19 wall model: [read][MFMA ~300][updates ~600][tail] phase
//     clusters re-aligned by the barrier each step = the remaining bubble.)
//  2) Eo hoisted in cell_update: all 4 gate exp2s issue together, dependent
//     tail shortened by ~2 trans latencies. Pure reorder.
//  3) x-writer's slot-51 store moved to the interval head (only depends on
//     xs; removes it from the pre-barrier tail).
// B-frag layout (r2-r13-verified): k -> ks=k>>5, lane=((k>>3)&3)*16+n, j=k&7.

#define TT 512
#define HH 50
#define BT 16
#define NTHR 1024  // 16 waves
#define L2E 1.44269504f

typedef _Float16 half8 __attribute__((ext_vector_type(8)));
typedef float floatx4 __attribute__((ext_vector_type(4)));

static __device__ __forceinline__ float fexp2(float x) { return __builtin_amdgcn_exp2f(x); }
static __device__ __forceinline__ float frcp(float x)  { return __builtin_amdgcn_rcpf(x); }

// PRE-SCALED cell update: inputs are already s_g*gate (s = -log2e, -log2e,
// -2log2e, -log2e for i,f,g,o). c' = R*[c*(1+Ei)(1+Eg) + (1-Eg)(1+Ef)],
// R = rcp((1+Ef)(1+Ei)(1+Eg)); h = sig(o)*tanh(c'), c clamped (NaN guard).
// Same ops as r17, Eo issued with the other exps (independent -> pure reorder).
static __device__ __forceinline__ float cell_update(float gi, float gf, float gg,
                                                    float go, float& c) {
    float Ei = fexp2(gi);
    float Eg = fexp2(gg);
    float Ef = fexp2(gf);
    float Eo = fexp2(go);
    float p1 = (1.0f + Ei) * (1.0f + Eg);
    float fe = 1.0f + Ef;
    float R  = frcp(fe * p1);
    c = R * (c * p1 + (1.0f - Eg) * fe);
    float cl = fminf(fmaxf(c, -18.0f), 18.0f);
    float Ec = fexp2(cl * (-2.0f * L2E));
    float Ro = frcp((1.0f + Eo) * (1.0f + Ec));
    return (1.0f - Ec) * Ro;
}

#define MFMA(a, b, c) __builtin_amdgcn_mfma_f32_16x16x32_f16((a), (b), (c), 0, 0, 0)

// ---------------- layer-0 waves: NJ tile-jobs, tiles tbase..tbase+NJ-1 ----------------
// Iter s computes h1(s) from h1(s-1) = H1[(s-1)&3]; writes H1[s&3].
// XW wave maintains x slot 51 of H1[s&3] with x(s+1).
template<int NJ, bool XW>
static __device__ __forceinline__ void run_l0(
    int tbase, int ln, _Float16 (*H1)[1024], const float* xs,
    const float* __restrict__ W_ih0, const float* __restrict__ W_hh0,
    const float* __restrict__ b_ih0, const float* __restrict__ b_hh0)
{
    const int m = ln & 15, q = ln >> 4;
    const float GSC[4] = { -L2E, -L2E, -2.0f * L2E, -L2E };

    half8 a0[NJ][2];
    float c[NJ];
    int   widx[NJ];
#pragma unroll
    for (int j = 0; j < NJ; ++j) {
        const int  tau  = tbase + j;
        const int  uA   = 4 * tau + (m >> 2);
        const int  gA   = m & 3;
        const bool rokA = (uA < HH);
        const int  wrow = gA * HH + uA;
        const float sA  = GSC[gA];
#pragma unroll
        for (int ks = 0; ks < 2; ++ks) {
            half8 h8;
#pragma unroll
            for (int jj = 0; jj < 8; ++jj) {
                int k = ks * 32 + q * 8 + jj;
                float w = 0.f;
                if (rokA) {
                    if (k < HH)       w = W_hh0[wrow * HH + k];
                    else if (k == 50) w = b_ih0[wrow] + b_hh0[wrow];
                    else if (k == 51) w = W_ih0[wrow];      // W_ih0 is [4H x 1]
                }
                h8[jj] = (_Float16)(sA * w);
            }
            a0[j][ks] = h8;
        }
        const int uC = 4 * tau + q;
        const int kh = (uC < HH) ? uC : (uC + 2);   // dummies 50,51 -> 52,53
        widx[j] = ((kh >> 5) * 64 + ((kh >> 3) & 3) * 16 + m) * 8 + (kh & 7);
        c[j] = 0.f;
    }

    __syncthreads();                       // A: staging + special slots visible

    // ---- t = 0: h1(0) from x(0) only (h=0), scalar path -> H1[0] ----
    {
        const float xv = xs[m];
#pragma unroll
        for (int j = 0; j < NJ; ++j) {
            const int  uC = 4 * (tbase + j) + q;
            const bool vC = (uC < HH);
            float g4[4];
#pragma unroll
            for (int g = 0; g < 4; ++g) {
                int rg = g * HH + (vC ? uC : 0);
                g4[g] = vC ? GSC[g] * ((b_ih0[rg] + b_hh0[rg]) + W_ih0[rg] * xv) : 0.f;
            }
            float h = cell_update(g4[0], g4[1], g4[2], g4[3], c[j]);
            H1[0][widx[j]] = (_Float16)h;
        }
    }
    __syncthreads();                       // B

    const floatx4 ZERO = { 0.f, 0.f, 0.f, 0.f };
    for (int s = 1; s <= 513; ++s) {
        if (s <= 511) {
            const _Float16* bufR = H1[(s - 1) & 3];
            _Float16*       bufW = H1[s & 3];
            if (XW) {
                if (ln < 16)            // x(s+1) -> slot 51; s=511 reads zero pad
                    bufW[(96 + ln) * 8 + 3] = (_Float16)xs[(s + 1) * BT + ln];
            }
            half8 b0 = *(const half8*)&bufR[(0  + ln) * 8];
            half8 b1 = *(const half8*)&bufR[(64 + ln) * 8];
#pragma unroll
            for (int j = 0; j < NJ; ++j) {      // fused: MFMA_j -> update_j -> write_j
                floatx4 a = MFMA(a0[j][0], b0, ZERO);
                a = MFMA(a0[j][1], b1, a);
                float h = cell_update(a[0], a[1], a[2], a[3], c[j]);
                bufW[widx[j]] = (_Float16)h;
            }
        }
        __syncthreads();
    }
}

// ---------------- layer-1 waves: NJ tile-jobs, tiles tbase..tbase+NJ-1 ----------------
// Iter s computes h2(s-2) from h1(s-2) (PREFETCHED last iter into p0,p1) and
// h2(s-3) = H2[(s-1)&1]; writes H2[s&1]. End of iter prefetches h1(s-1).
template<int NJ>
static __device__ __forceinline__ void run_l1(
    int tbase, int ln, _Float16 (*H1)[1024], _Float16 (*H2)[1024],
    const float* __restrict__ W_ih1, const float* __restrict__ W_hh1,
    const float* __restrict__ b_ih1, const float* __restrict__ b_hh1)
{
    const int m = ln & 15, q = ln >> 4;
    const float GSC[4] = { -L2E, -L2E, -2.0f * L2E, -L2E };

    half8 a1[NJ][4];       // virtual K=128: [W_ih1 | bias@50 | 0 | W_hh1@64.. | 0]
    float c[NJ];
    int   widx[NJ];
#pragma unroll
    for (int j = 0; j < NJ; ++j) {
        const int  tau  = tbase + j;
        const int  uA   = 4 * tau + (m >> 2);
        const int  gA   = m & 3;
        const bool rokA = (uA < HH);
        const int  wrow = gA * HH + uA;
        const float sA  = GSC[gA];
#pragma unroll
        for (int ks = 0; ks < 4; ++ks) {
            half8 h8;
#pragma unroll
            for (int jj = 0; jj < 8; ++jj) {
                int k = ks * 32 + q * 8 + jj;
                float w = 0.f;
                if (rokA) {
                    if (k < HH)                      w = W_ih1[wrow * HH + k];
                    else if (k == 50)                w = b_ih1[wrow] + b_hh1[wrow];
                    else if (k >= 64 && k < 64 + HH) w = W_hh1[wrow * HH + (k - 64)];
                }
                h8[jj] = (_Float16)(sA * w);
            }
            a1[j][ks] = h8;
        }
        const int uC = 4 * tau + q;
        const int kh = (uC < HH) ? uC : (uC + 2);   // dummies -> 52,53 (zero-A)
        widx[j] = ((kh >> 5) * 64 + ((kh >> 3) & 3) * 16 + m) * 8 + (kh & 7);
        c[j] = 0.f;
    }

    __syncthreads();                       // A
    __syncthreads();                       // B (L0 prologue)

    half8 p0 = {}, p1 = {};                // prefetched h1 B-frags
    const floatx4 ZERO = { 0.f, 0.f, 0.f, 0.f };
    for (int s = 1; s <= 513; ++s) {
        if (s >= 2) {
            const _Float16* h2R = H2[(s - 1) & 1];
            _Float16*       h2W = H2[s & 1];
            half8 b2 = *(const half8*)&h2R[(0  + ln) * 8];
            half8 b3 = *(const half8*)&h2R[(64 + ln) * 8];
#pragma unroll
            for (int j = 0; j < NJ; ++j) {      // fused: MFMA_j -> update_j -> write_j
                floatx4 a = MFMA(a1[j][0], p0, ZERO);   // p0/p1 in regs: no LDS wait
                a = MFMA(a1[j][1], p1, a);
                a = MFMA(a1[j][2], b2, a);
                a = MFMA(a1[j][3], b3, a);
                float h = cell_update(a[0], a[1], a[2], a[3], c[j]);
                h2W[widx[j]] = (_Float16)h;
            }
        }
        {   // prefetch h1(s-1) for next iter (valid: written before barrier(s-1);
            // reads complete pre-barrier via the compiler's lgkmcnt(0) drain)
            const _Float16* h1R = H1[(s - 1) & 3];
            p0 = *(const half8*)&h1R[(0  + ln) * 8];
            p1 = *(const half8*)&h1R[(64 + ln) * 8];
        }
        __syncthreads();
    }
}

__global__ __launch_bounds__(NTHR, 4) void lstm_mfma(
    const float* __restrict__ x,
    const float* __restrict__ W_ih0, const float* __restrict__ W_hh0,
    const float* __restrict__ b_ih0, const float* __restrict__ b_hh0,
    const float* __restrict__ W_ih1, const float* __restrict__ W_hh1,
    const float* __restrict__ b_ih1, const float* __restrict__ b_hh1,
    const float* __restrict__ W_fc,  const float* __restrict__ b_fc,
    float* __restrict__ out)
{
    __shared__ __align__(16) _Float16 H1[4][1024];   // h1 ring + bias/x slots
    __shared__ __align__(16) _Float16 H2[2][1024];   // h2 ring
    __shared__ float xs[(TT + 1) * BT];              // +1 zero pad row

    const int tid = threadIdx.x;
    const int ln  = tid & 63;
    const int wv  = tid >> 6;              // 0..15
    const int b0g = blockIdx.x * BT;

    // ---------------- one-time staging ----------------
    for (int i = tid; i < BT * TT; i += NTHR) {
        int b = i & 15, t = i >> 4;
        xs[t * BT + b] = x[(size_t)(b0g + b) * TT + t];
    }
    if (tid < BT) xs[TT * BT + tid] = 0.f;
    for (int i = tid; i < 4 * 1024; i += NTHR) ((_Float16*)H1)[i] = (_Float16)0.f;
    for (int i = tid; i < 2 * 1024; i += NTHR) ((_Float16*)H2)[i] = (_Float16)0.f;
    __syncthreads();
    if (tid < 16) {
        // bias slot k=50 (ks=1, lane 32+n, j=2) == 1.0, all 4 ring buffers
#pragma unroll
        for (int r = 0; r < 4; ++r) H1[r][(96 + tid) * 8 + 2] = (_Float16)1.0f;
        // x(1) -> slot k=51 of H1[0] (read by L0 at s=1)
        H1[0][(96 + tid) * 8 + 3] = (_Float16)xs[BT + tid];
    }
    // (visibility of the above: covered by run_*'s first __syncthreads)

    // job split (13 L0 jobs on waves 0-7, 13 L1 jobs on waves 8-15), chosen so
    // round-robin wave->SIMD (wv&3) gives per-SIMD update counts {7,6,6,7}:
    //   L0: w0-w4: 2 jobs; w5, w6(x-writer), w7: 1 job
    //   L1: w8,w9,w10: 1 job; w11-w15: 2 jobs
    if (wv < 8) {
        if (wv < 5)
            run_l0<2, false>(2 * wv, ln, H1, xs, W_ih0, W_hh0, b_ih0, b_hh0);
        else if (wv == 6)
            run_l0<1, true>(11, ln, H1, xs, W_ih0, W_hh0, b_ih0, b_hh0);
        else
            run_l0<1, false>(wv == 5 ? 10 : 12, ln, H1, xs,
                             W_ih0, W_hh0, b_ih0, b_hh0);
    } else {
        const int w = wv - 8;
        if (w < 3)
            run_l1<1>(w, ln, H1, H2, W_ih1, W_hh1, b_ih1, b_hh1);
        else
            run_l1<2>(3 + 2 * (w - 3), ln, H1, H2,
                      W_ih1, W_hh1, b_ih1, b_hh1);
    }

    // -------- FC epilogue: h2(511) written at iter 513 -> H2[1] --------
    if (tid < BT) {
        float a = b_fc[0];
        for (int u = 0; u < HH; ++u) {
            int idx = ((u >> 5) * 64 + ((u >> 3) & 3) * 16 + tid) * 8 + (u & 7);
            a = fmaf((float)H2[1][idx], W_fc[u], a);
        }
        out[b0g + tid] = a;
    }
}

extern "C" void kernel_launch(void* const* d_in, const int* in_sizes, int n_in,
                              void* d_out, int out_size, void* d_ws, size_t ws_size,
                              hipStream_t stream) {
    const float* x     = (const float*)d_in[0];
    const float* W_ih0 = (const float*)d_in[1];
    const float* W_hh0 = (const float*)d_in[2];
    const float* b_ih0 = (const float*)d_in[3];
    const float* b_hh0 = (const float*)d_in[4];
    const float* W_ih1 = (const float*)d_in[5];
    const float* W_hh1 = (const float*)d_in[6];
    const float* b_ih1 = (const float*)d_in[7];
    const float* b_hh1 = (const float*)d_in[8];
    const float* W_fc  = (const float*)d_in[9];
    const float* b_fc  = (const float*)d_in[10];
    float* out = (float*)d_out;

    dim3 grid(4096 / BT);   // 256 blocks = 1/CU
    dim3 block(NTHR);       // 16 waves
    lstm_mfma<<<grid, block, 0, stream>>>(x, W_ih0, W_hh0, b_ih0, b_hh0,
                                          W_ih1, W_hh1, b_ih1, b_hh1,
                                          W_fc, b_fc, out);
}